// Round 6
// baseline (477.535 us; speedup 1.0000x reference)
//
#include <hip/hip_runtime.h>

#define IN_DIM 32
#define OUT_DIM 64
#define BUCKET_SHIFT 8                 // 256 nodes per bucket
#define NODES_PER_BUCKET 256
#define NBUCK_MAX 512
#define EPB 8192                       // edges per hist/reorder block

// K1: per-block histogram of dst buckets, written bucket-major [bucket][block].
__global__ __launch_bounds__(512) void hist_kernel(
    const int* __restrict__ dst, int* __restrict__ counts,
    int n_edges, int nb1, int nbuck) {
    __shared__ int hist[NBUCK_MAX];
    int tx = threadIdx.x;
    for (int i = tx; i < nbuck; i += 512) hist[i] = 0;
    __syncthreads();
    int base = blockIdx.x * EPB;
#pragma unroll
    for (int j = 0; j < EPB / 512; ++j) {
        int e = base + j * 512 + tx;
        if (e < n_edges) atomicAdd(&hist[dst[e] >> BUCKET_SHIFT], 1);
    }
    __syncthreads();
    for (int i = tx; i < nbuck; i += 512) counts[i * nb1 + blockIdx.x] = hist[i];
}

// K2: per-block exclusive scan (Hillis-Steele in LDS), writes block sums.
__global__ __launch_bounds__(256) void scan1_kernel(
    const int* __restrict__ counts, int* __restrict__ offsets,
    int* __restrict__ block_sums, int n) {
    __shared__ int tmp[256];
    int tx = threadIdx.x;
    int idx = blockIdx.x * 256 + tx;
    int v = (idx < n) ? counts[idx] : 0;
    tmp[tx] = v;
    __syncthreads();
    for (int off = 1; off < 256; off <<= 1) {
        int t = (tx >= off) ? tmp[tx - off] : 0;
        __syncthreads();
        tmp[tx] += t;
        __syncthreads();
    }
    if (idx < n) offsets[idx] = tmp[tx] - v;  // exclusive
    if (tx == 255) block_sums[blockIdx.x] = tmp[255];
}

// K3: exclusive scan of block sums (nb <= 512), one block.
__global__ __launch_bounds__(512) void scan2_kernel(int* __restrict__ block_sums, int nb) {
    __shared__ int tmp[512];
    int tx = threadIdx.x;
    int v = (tx < nb) ? block_sums[tx] : 0;
    tmp[tx] = v;
    __syncthreads();
    for (int off = 1; off < 512; off <<= 1) {
        int t = (tx >= off) ? tmp[tx - off] : 0;
        __syncthreads();
        tmp[tx] += t;
        __syncthreads();
    }
    if (tx < nb) block_sums[tx] = tmp[tx] - v;  // exclusive
}

// K4: add scanned block offsets in place.
__global__ __launch_bounds__(256) void finalize_kernel(
    int* __restrict__ offsets, const int* __restrict__ block_sums, int n) {
    int idx = blockIdx.x * 256 + threadIdx.x;
    if (idx < n) offsets[idx] += block_sums[blockIdx.x];
}

// K5: reorder edges into bucket-major runs. Positions claimed via LDS
// cursors (no device atomics). Each (block,bucket) run (~21 edges x 4B) is
// written by exactly one block -> lines fill within one XCD's L2 before
// writeback (fixes round-3's 105MB partial-line write traffic).
// Record packs src (17b) and dst's in-bucket index (8b) into one int.
__global__ __launch_bounds__(512) void reorder_kernel(
    const int* __restrict__ src, const int* __restrict__ dst,
    const int* __restrict__ offsets, int* __restrict__ rec,
    int n_edges, int nb1, int nbuck) {
    __shared__ int cur[NBUCK_MAX];
    int tx = threadIdx.x;
    for (int i = tx; i < nbuck; i += 512) cur[i] = offsets[i * nb1 + blockIdx.x];
    __syncthreads();
    int base = blockIdx.x * EPB;
#pragma unroll
    for (int j = 0; j < EPB / 512; ++j) {
        int e = base + j * 512 + tx;
        if (e < n_edges) {
            int d = dst[e];
            int pos = atomicAdd(&cur[d >> BUCKET_SHIFT], 1);
            rec[pos] = (src[e] << BUCKET_SHIFT) | (d & (NODES_PER_BUCKET - 1));
        }
    }
}

// K6: one block per bucket. Aggregate 256 nodes x 32 dims in LDS (32KB) with
// LDS float atomics (lane = dim -> banks 0..31, conflict-free), gathering
// feature rows (128B coalesced, L2/LLC-resident). Then project through
// LDS-staged W (64 consecutive cols/wave -> 2 lanes/bank, free) and write
// out directly. 40.3KB LDS -> 2-3 blocks/CU; 8-deep edge unroll for MLP.
__global__ __launch_bounds__(512) void aggproj_kernel(
    const float* __restrict__ feature, const int* __restrict__ offsets,
    const int* __restrict__ rec, const float* __restrict__ W,
    const float* __restrict__ b, float* __restrict__ out,
    int n_nodes, int n_edges, int nb1, int nbuck) {
    __shared__ float h[NODES_PER_BUCKET * IN_DIM];  // 32 KB
    __shared__ float Ws[IN_DIM * OUT_DIM];          // 8 KB
    __shared__ float bs[OUT_DIM];
    int tx = threadIdx.x;
    int bk = blockIdx.x;

    for (int i = tx; i < NODES_PER_BUCKET * IN_DIM; i += 512) h[i] = 0.0f;
    for (int i = tx; i < IN_DIM * OUT_DIM; i += 512) Ws[i] = W[i];
    if (tx < OUT_DIM) bs[tx] = b[tx];

    int start = offsets[bk * nb1];
    int end = (bk + 1 < nbuck) ? offsets[(bk + 1) * nb1] : n_edges;
    __syncthreads();

    int grp = tx >> 5, lane = tx & 31;  // 16 groups of 32 lanes (one dim each)
    for (int e0 = start + grp * 8; e0 < end; e0 += 16 * 8) {
#pragma unroll
        for (int j = 0; j < 8; ++j) {
            int e = e0 + j;
            int r = (e < end) ? rec[e] : 0;
            // OOB lanes add 0.0f to node 0 — harmless, keeps it branchless.
            float v = (e < end) ? feature[(long long)(r >> BUCKET_SHIFT) * IN_DIM + lane] : 0.0f;
            atomicAdd(&h[(r & (NODES_PER_BUCKET - 1)) * IN_DIM + lane], v);
        }
    }
    __syncthreads();

    int node0 = bk * NODES_PER_BUCKET;
#pragma unroll
    for (int it = 0; it < NODES_PER_BUCKET * OUT_DIM / 512; ++it) {  // 32 iters
        int idx = it * 512 + tx;
        int col = idx & 63, nl = idx >> 6;
        int node = node0 + nl;
        if (node >= n_nodes) break;  // wave-uniform (nl constant per wave)
        float acc = bs[col];
#pragma unroll
        for (int k = 0; k < IN_DIM; ++k)
            acc += h[nl * IN_DIM + k] * Ws[k * OUT_DIM + col];
        out[(long long)node * OUT_DIM + col] = acc;
    }
}

extern "C" void kernel_launch(void* const* d_in, const int* in_sizes, int n_in,
                              void* d_out, int out_size, void* d_ws, size_t ws_size,
                              hipStream_t stream) {
    const float* feature = (const float*)d_in[0];
    const int* src = (const int*)d_in[1];
    const int* dst = (const int*)d_in[2];
    const float* W = (const float*)d_in[3];
    const float* b = (const float*)d_in[4];
    float* out = (float*)d_out;

    int n_nodes = in_sizes[0] / IN_DIM;  // 100000
    int n_edges = in_sizes[1];           // 1600000

    int nb1 = (n_edges + EPB - 1) / EPB;                          // 196
    int nbuck = (n_nodes + NODES_PER_BUCKET - 1) / NODES_PER_BUCKET;  // 391
    int ncounts = nbuck * nb1;                                    // 76636

    // Workspace layout (ints): counts | offsets | block_sums(512) | rec
    int* counts = (int*)d_ws;
    int* offsets = counts + ncounts;
    int* block_sums = offsets + ncounts;
    int* rec = block_sums + 512;

    hist_kernel<<<nb1, 512, 0, stream>>>(dst, counts, n_edges, nb1, nbuck);
    int sb = (ncounts + 255) / 256;  // 300 <= 512
    scan1_kernel<<<sb, 256, 0, stream>>>(counts, offsets, block_sums, ncounts);
    scan2_kernel<<<1, 512, 0, stream>>>(block_sums, sb);
    finalize_kernel<<<sb, 256, 0, stream>>>(offsets, block_sums, ncounts);
    reorder_kernel<<<nb1, 512, 0, stream>>>(src, dst, offsets, rec, n_edges, nb1, nbuck);
    aggproj_kernel<<<nbuck, 512, 0, stream>>>(feature, offsets, rec, W, b, out,
                                              n_nodes, n_edges, nb1, nbuck);
}